// Round 1
// baseline (31766.321 us; speedup 1.0000x reference)
//
#include <hip/hip_runtime.h>

#define BB 128
#define TT 2048
#define FF 64
#define HH 256
#define GG 1024   // 4*HH
#define KZ 320    // HH + FF
#define KP 328    // padded LDS row length (ushort elems), 656B = 41*16

typedef short short8 __attribute__((ext_vector_type(8)));
typedef float f32x4 __attribute__((ext_vector_type(4)));

// f32 -> bf16 bits, round-to-nearest-even
__device__ inline unsigned short f2b(float f) {
  unsigned int u = __builtin_bit_cast(unsigned int, f);
  u += 0x7fffu + ((u >> 16) & 1u);
  return (unsigned short)(u >> 16);
}

// ---------------- prep: pack fragment-linear bf16 weights into ws ----------------
// ws layout (ushort units):
//   We'' : [64 tiles][10 ks][64 lanes][8]  @ 0        (327680 ushorts)
//   Wd'' : same                            @ 327680
//   Wo'' : [ 4 tiles][ 8 ks][64 lanes][8]  @ 655360   (16384 ushorts)
// tile c covers gate-cols [16c,16c+16); k<256 -> Whh[col][k], k>=256 -> Wih[col][k-256]
__global__ void prep_kernel(const float* __restrict__ Wih_e, const float* __restrict__ Whh_e,
                            const float* __restrict__ Wih_d, const float* __restrict__ Whh_d,
                            const float* __restrict__ Wout, unsigned short* __restrict__ ws) {
  int idx = blockIdx.x * blockDim.x + threadIdx.x;
  const int NW = 64 * 10 * 64;  // 40960 chunks per weight matrix
  if (idx < 2 * NW) {
    int q = (idx < NW) ? idx : idx - NW;
    const float* Wih = (idx < NW) ? Wih_e : Wih_d;
    const float* Whh = (idx < NW) ? Whh_e : Whh_d;
    unsigned short* dst = ws + (idx < NW ? 0 : NW * 8) + q * 8;
    int c = q / 640, rem = q % 640;
    int ks = rem / 64, l = rem % 64;
    int col = c * 16 + (l & 15);
    int k0 = ks * 32 + (l >> 4) * 8;
#pragma unroll
    for (int e = 0; e < 8; e++) {
      int k = k0 + e;
      float v = (k < HH) ? Whh[col * HH + k] : Wih[col * FF + (k - HH)];
      dst[e] = f2b(v);
    }
  } else if (idx < 2 * NW + 2048) {
    int q = idx - 2 * NW;
    unsigned short* dst = ws + 2 * NW * 8 + q * 8;
    int c = q / 512, rem = q % 512;
    int ks = rem / 64, l = rem % 64;
    int f = c * 16 + (l & 15);
    int k0 = ks * 32 + (l >> 4) * 8;
#pragma unroll
    for (int e = 0; e < 8; e++) dst[e] = f2b(Wout[f * HH + k0 + e]);
  }
}

// ---------------- main: 8 blocks x 16 batch rows, fully fused enc+dec ----------------
__global__ __launch_bounds__(512) void lstm_kernel(
    const float* __restrict__ xg, const float* __restrict__ b_e,
    const float* __restrict__ b_d, const float* __restrict__ bout,
    const unsigned short* __restrict__ wsu, float* __restrict__ out) {
  __shared__ unsigned short zb[16][KP];  // z = [h(256) ; x(64)] bf16, padded
  const int tid = threadIdx.x;
  const int l = tid & 63, w = tid >> 6;  // 8 waves
  const int ln = l & 15, lk = l >> 4;
  const int b0 = blockIdx.x * 16;

  const short8* We = (const short8*)wsu;
  const short8* Wd = (const short8*)(wsu + 327680);
  const short8* Wo = (const short8*)(wsu + 655360);

  // hoisted per-lane biases: gate g, sub-tile s -> col = g*256 + 32w + 16s + ln
  float be_[4][2], bd_[4][2];
#pragma unroll
  for (int g = 0; g < 4; g++)
#pragma unroll
    for (int s = 0; s < 2; s++) {
      int col = g * 256 + 32 * w + 16 * s + ln;
      be_[g][s] = b_e[col];
      bd_[g][s] = b_d[col];
    }
  float bo_ = bout[16 * (w & 3) + ln];

  // zero h region (h0 = 0)
  for (int i = tid; i < 16 * 256; i += 512) zb[i >> 8][i & 255] = 0;

  float creg[2][4];  // c state: (sub-tile s, row-reg r) for unit 32w+16s+ln, row lk*4+r
#pragma unroll
  for (int s = 0; s < 2; s++)
#pragma unroll
    for (int r = 0; r < 4; r++) creg[s][r] = 0.f;

  // x loader: 2 elems/thread: elem e=2*tid -> row e>>6, feat e&63
  const int xr0 = tid >> 5;
  const int xf0 = (tid & 31) * 2;
  float xv0 = xg[((size_t)(b0 + xr0) * TT + 0) * FF + xf0];
  float xv1 = xg[((size_t)(b0 + xr0) * TT + 0) * FF + xf0 + 1];

#pragma unroll 1
  for (int it = 0; it < 2 * TT; ++it) {
    const bool dec = (it >= TT);
    const int t = dec ? (2 * TT - 1 - it) : it;

    // stage x(t) into LDS (h region holds h from prev step)
    zb[xr0][HH + xf0] = f2b(xv0);
    zb[xr0][HH + xf0 + 1] = f2b(xv1);
    __syncthreads();  // barrier A: z complete

    // A fragments: lane holds z[row=ln][k = ks*32 + lk*8 .. +8]
    short8 afr[10];
#pragma unroll
    for (int ks = 0; ks < 10; ks++)
      afr[ks] = *(const short8*)&zb[ln][ks * 32 + lk * 8];
    __syncthreads();  // barrier B: all A reads done -> LDS may be overwritten

    // prefetch next step's x (hides HBM latency under MFMA/act)
    {
      int it2 = it + 1;
      if (it2 >= 2 * TT) it2 = 0;
      int t2 = (it2 < TT) ? it2 : (2 * TT - 1 - it2);
      const float* px = &xg[((size_t)(b0 + xr0) * TT + t2) * FF + xf0];
      xv0 = px[0];
      xv1 = px[1];
    }

    // gates GEMM: wave w owns units [32w,32w+32): tiles c = g*16 + 2w + s
    const short8* Wt = dec ? Wd : We;
    f32x4 acc[4][2];
#pragma unroll
    for (int g = 0; g < 4; g++)
#pragma unroll
      for (int s = 0; s < 2; s++) acc[g][s] = f32x4{0.f, 0.f, 0.f, 0.f};

#pragma unroll
    for (int g = 0; g < 4; g++) {
#pragma unroll
      for (int s = 0; s < 2; s++) {
        const short8* p = Wt + ((g * 16 + 2 * w + s) * 10) * 64 + l;
#pragma unroll
        for (int ks = 0; ks < 10; ks++)
          acc[g][s] = __builtin_amdgcn_mfma_f32_16x16x32_bf16(afr[ks], p[ks * 64], acc[g][s], 0, 0, 0);
      }
    }

    // decoder: out[:,t] = h_old @ Wout^T + bout (uses afr = old h, k<256)
    if (dec && w < 4) {
      f32x4 oa = f32x4{0.f, 0.f, 0.f, 0.f};
      const short8* p = Wo + (w * 8) * 64 + l;
#pragma unroll
      for (int ks = 0; ks < 8; ks++)
        oa = __builtin_amdgcn_mfma_f32_16x16x32_bf16(afr[ks], p[ks * 64], oa, 0, 0, 0);
#pragma unroll
      for (int r = 0; r < 4; r++)
        out[((size_t)(b0 + lk * 4 + r) * TT + t) * FF + 16 * w + ln] = oa[r] + bo_;
    }

    // activations + state update; D layout: col = ln (unit), row = lk*4 + r (batch)
#pragma unroll
    for (int s = 0; s < 2; s++) {
      float bi = dec ? bd_[0][s] : be_[0][s];
      float bf = dec ? bd_[1][s] : be_[1][s];
      float bg = dec ? bd_[2][s] : be_[2][s];
      float bo2 = dec ? bd_[3][s] : be_[3][s];
#pragma unroll
      for (int r = 0; r < 4; r++) {
        float gi = acc[0][s][r] + bi;
        float gf = acc[1][s][r] + bf;
        float gg = acc[2][s][r] + bg;
        float go = acc[3][s][r] + bo2;
        float si = 1.f / (1.f + __expf(-gi));
        float sf = 1.f / (1.f + __expf(-gf));
        float tg = 1.f - 2.f / (__expf(2.f * gg) + 1.f);  // tanh
        float so = 1.f / (1.f + __expf(-go));
        float cn = sf * creg[s][r] + si * tg;
        creg[s][r] = cn;
        float hn = so * (1.f - 2.f / (__expf(2.f * cn) + 1.f));
        zb[lk * 4 + r][32 * w + 16 * s + ln] = f2b(hn);  // h for next step
      }
    }
  }
}

extern "C" void kernel_launch(void* const* d_in, const int* in_sizes, int n_in,
                              void* d_out, int out_size, void* d_ws, size_t ws_size,
                              hipStream_t stream) {
  const float* ts    = (const float*)d_in[0];
  const float* Wih_e = (const float*)d_in[1];
  const float* Whh_e = (const float*)d_in[2];
  const float* b_e   = (const float*)d_in[3];
  const float* Wih_d = (const float*)d_in[4];
  const float* Whh_d = (const float*)d_in[5];
  const float* b_d   = (const float*)d_in[6];
  const float* Wout  = (const float*)d_in[7];
  const float* bout  = (const float*)d_in[8];
  unsigned short* ws = (unsigned short*)d_ws;
  float* out = (float*)d_out;

  // 2*40960 + 2048 = 83968 pack chunks, 256 threads/block -> 328 blocks
  prep_kernel<<<328, 256, 0, stream>>>(Wih_e, Whh_e, Wih_d, Whh_d, Wout, ws);
  lstm_kernel<<<8, 512, 0, stream>>>(ts, b_e, b_d, bout, ws, out);
}

// Round 2
// 22749.548 us; speedup vs baseline: 1.3963x; 1.3963x over previous
//
#include <hip/hip_runtime.h>

#define TT 2048
#define FF 64
#define HH 256

typedef short short8 __attribute__((ext_vector_type(8)));
typedef float f32x4 __attribute__((ext_vector_type(4)));

// f32 -> bf16 bits, round-to-nearest-even
__device__ inline unsigned short f2b(float f) {
  unsigned int u = __builtin_bit_cast(unsigned int, f);
  u += 0x7fffu + ((u >> 16) & 1u);
  return (unsigned short)(u >> 16);
}

// ws layout (ushort units), all fragment-linear [tile][ks][lane][8]:
//  WhhE @0       [64][8][64][8] = 262144
//  WihE @262144  [64][2][64][8] =  65536
//  WhhD @327680                   262144
//  WihD @589824                    65536
//  WoutP @655360 [ 4][8][64][8] =  16384
__global__ void prep_kernel(const float* __restrict__ Wih_e, const float* __restrict__ Whh_e,
                            const float* __restrict__ Wih_d, const float* __restrict__ Whh_d,
                            const float* __restrict__ Wout, unsigned short* __restrict__ ws) {
  int idx = blockIdx.x * blockDim.x + threadIdx.x;
  if (idx >= 83968) return;
  const float* src; unsigned short* dst; int q, kdim;
  if (idx < 32768)      { q = idx;         src = Whh_e; dst = ws + 0      + q * 8; kdim = HH; }
  else if (idx < 40960) { q = idx - 32768; src = Wih_e; dst = ws + 262144 + q * 8; kdim = FF; }
  else if (idx < 73728) { q = idx - 40960; src = Whh_d; dst = ws + 327680 + q * 8; kdim = HH; }
  else if (idx < 81920) { q = idx - 73728; src = Wih_d; dst = ws + 589824 + q * 8; kdim = FF; }
  else                  { q = idx - 81920; src = Wout;  dst = ws + 655360 + q * 8; kdim = HH; }
  int ksPerTile = (kdim == HH) ? 8 : 2;
  int per = ksPerTile * 64;
  int tile = q / per, rem = q % per;
  int ks = rem / 64, l = rem % 64;
  int col = tile * 16 + (l & 15);
  int k0 = ks * 32 + (l >> 4) * 8;
#pragma unroll
  for (int e = 0; e < 8; e++) dst[e] = f2b(src[col * kdim + k0 + e]);
}

// 8 blocks x 16 batch rows, 8 waves; wave owns 32 hidden units (8 col-tiles).
// Residency: Wih in LDS (128KB), Whh ks0..2 in regs (96/wave), stream ks3..7.
__global__ __launch_bounds__(512, 2) void lstm_kernel(
    const float* __restrict__ xg, const float* __restrict__ b_e,
    const float* __restrict__ b_d, const float* __restrict__ bout,
    const unsigned short* __restrict__ wsu, float* __restrict__ out) {
  extern __shared__ unsigned short smem[];       // [16*328 zb | 65536 wih]
  unsigned short* zbp = smem;
  short8* wihLds = (short8*)(smem + 5248);
#define ZB(r, c) zbp[(r) * 328 + (c)]
  const int tid = threadIdx.x;
  const int l = tid & 63, w = tid >> 6;
  const int ln = l & 15, lk = l >> 4;
  const int b0 = blockIdx.x * 16;

  int tIdx[8];
#pragma unroll
  for (int c = 0; c < 8; c++) tIdx[c] = (c >> 1) * 16 + 2 * w + (c & 1);

  const short8* Wo = (const short8*)(wsu + 655360);

  short8 res[8][3];   // register-resident Whh ks=0..2
  float b_[4][2];     // current-phase biases
  float bo_ = bout[16 * (w & 3) + ln];

  for (int i = tid; i < 16 * 256; i += 512) ZB(i >> 8, i & 255) = 0;

  float creg[2][4];
#pragma unroll
  for (int s = 0; s < 2; s++)
#pragma unroll
    for (int r = 0; r < 4; r++) creg[s][r] = 0.f;

  const int xr0 = tid >> 5, xf0 = (tid & 31) * 2;
  float xv0 = xg[(size_t)(b0 + xr0) * TT * FF + xf0];
  float xv1 = xg[(size_t)(b0 + xr0) * TT * FF + xf0 + 1];

#pragma unroll 1
  for (int it = 0; it < 2 * TT; ++it) {
    const bool dec = (it >= TT);
    const int t = dec ? (2 * TT - 1 - it) : it;

    if (it == 0 || it == TT) {      // phase init: load resident weights + biases
      if (it) __syncthreads();      // all prior-phase LDS reads done
      const short8* WhhP = (const short8*)(wsu + (it ? 327680 : 0));
      const short8* WihP = (const short8*)(wsu + (it ? 589824 : 262144));
      const float* bias = it ? b_d : b_e;
      for (int i = tid; i < 8192; i += 512) wihLds[i] = WihP[i];
#pragma unroll
      for (int c = 0; c < 8; c++)
#pragma unroll
        for (int ks = 0; ks < 3; ks++) res[c][ks] = WhhP[(tIdx[c] * 8 + ks) * 64 + l];
#pragma unroll
      for (int g = 0; g < 4; g++)
#pragma unroll
        for (int s = 0; s < 2; s++) b_[g][s] = bias[g * 256 + 32 * w + 16 * s + ln];
    }

    ZB(xr0, HH + xf0) = f2b(xv0);
    ZB(xr0, HH + xf0 + 1) = f2b(xv1);
    __syncthreads();  // barrier A: z = [h|x] complete (and phase-init LDS visible)

    short8 afr[10];   // z fragments: ks0..7 = h, ks8..9 = x
#pragma unroll
    for (int ks = 0; ks < 10; ks++) afr[ks] = *(const short8*)&ZB(ln, ks * 32 + lk * 8);
    __syncthreads();  // barrier B: all z reads done -> zb writable

    {  // prefetch next step's x (hidden under MFMA phase)
      int it2 = it + 1;
      if (it2 >= 2 * TT) it2 = 0;
      int t2 = (it2 < TT) ? it2 : (2 * TT - 1 - it2);
      const float* px = &xg[((size_t)(b0 + xr0) * TT + t2) * FF + xf0];
      xv0 = px[0];
      xv1 = px[1];
    }

    const short8* WhhS = (const short8*)(wsu + (dec ? 327680 : 0));
    f32x4 acc[4][2];
#pragma unroll
    for (int g = 0; g < 4; g++)
#pragma unroll
      for (int s = 0; s < 2; s++) acc[g][s] = f32x4{0.f, 0.f, 0.f, 0.f};

    short8 str[2][5];  // double-buffered streamed Whh ks=3..7
#pragma unroll
    for (int j = 0; j < 5; j++) str[0][j] = WhhS[(tIdx[0] * 8 + 3 + j) * 64 + l];

#pragma unroll
    for (int c = 0; c < 8; c++) {
      const int g = c >> 1, s = c & 1;
      if (c < 7) {
#pragma unroll
        for (int j = 0; j < 5; j++)
          str[(c + 1) & 1][j] = WhhS[(tIdx[c + 1] * 8 + 3 + j) * 64 + l];
      }
#pragma unroll
      for (int ks = 0; ks < 3; ks++)
        acc[g][s] = __builtin_amdgcn_mfma_f32_16x16x32_bf16(afr[ks], res[c][ks], acc[g][s], 0, 0, 0);
#pragma unroll
      for (int j = 0; j < 5; j++)
        acc[g][s] = __builtin_amdgcn_mfma_f32_16x16x32_bf16(afr[3 + j], str[c & 1][j], acc[g][s], 0, 0, 0);
      acc[g][s] = __builtin_amdgcn_mfma_f32_16x16x32_bf16(afr[8], wihLds[(tIdx[c] * 2 + 0) * 64 + l], acc[g][s], 0, 0, 0);
      acc[g][s] = __builtin_amdgcn_mfma_f32_16x16x32_bf16(afr[9], wihLds[(tIdx[c] * 2 + 1) * 64 + l], acc[g][s], 0, 0, 0);
    }

    // decoder output: out[:,t] = h_old @ Wout^T + bout (afr ks0..7 = old h)
    if (dec && w < 4) {
      f32x4 oa = f32x4{0.f, 0.f, 0.f, 0.f};
      const short8* p = Wo + (w * 8) * 64 + l;
#pragma unroll
      for (int ks = 0; ks < 8; ks++)
        oa = __builtin_amdgcn_mfma_f32_16x16x32_bf16(afr[ks], p[ks * 64], oa, 0, 0, 0);
#pragma unroll
      for (int r = 0; r < 4; r++)
        out[((size_t)(b0 + lk * 4 + r) * TT + t) * FF + 16 * w + ln] = oa[r] + bo_;
    }

    // activations + state update; D layout: col=ln (unit), row=lk*4+r (batch)
#pragma unroll
    for (int s = 0; s < 2; s++) {
#pragma unroll
      for (int r = 0; r < 4; r++) {
        float gi = acc[0][s][r] + b_[0][s];
        float gf = acc[1][s][r] + b_[1][s];
        float gg = acc[2][s][r] + b_[2][s];
        float go = acc[3][s][r] + b_[3][s];
        float si = 1.f / (1.f + __expf(-gi));
        float sf = 1.f / (1.f + __expf(-gf));
        float tg = 1.f - 2.f / (__expf(2.f * gg) + 1.f);
        float so = 1.f / (1.f + __expf(-go));
        float cn = sf * creg[s][r] + si * tg;
        creg[s][r] = cn;
        float hn = so * (1.f - 2.f / (__expf(2.f * cn) + 1.f));
        ZB(lk * 4 + r, 32 * w + 16 * s + ln) = f2b(hn);
      }
    }
  }
#undef ZB
}

extern "C" void kernel_launch(void* const* d_in, const int* in_sizes, int n_in,
                              void* d_out, int out_size, void* d_ws, size_t ws_size,
                              hipStream_t stream) {
  const float* ts    = (const float*)d_in[0];
  const float* Wih_e = (const float*)d_in[1];
  const float* Whh_e = (const float*)d_in[2];
  const float* b_e   = (const float*)d_in[3];
  const float* Wih_d = (const float*)d_in[4];
  const float* Whh_d = (const float*)d_in[5];
  const float* b_d   = (const float*)d_in[6];
  const float* Wout  = (const float*)d_in[7];
  const float* bout  = (const float*)d_in[8];
  unsigned short* ws = (unsigned short*)d_ws;
  float* out = (float*)d_out;

  const int ldsBytes = (5248 + 65536) * 2;  // 141568 B
  (void)hipFuncSetAttribute((const void*)lstm_kernel,
                            hipFuncAttributeMaxDynamicSharedMemorySize, ldsBytes);

  prep_kernel<<<328, 256, 0, stream>>>(Wih_e, Whh_e, Wih_d, Whh_d, Wout, ws);
  lstm_kernel<<<8, 512, ldsBytes, stream>>>(ts, b_e, b_d, bout, ws, out);
}